// Round 12
// baseline (52.869 us; speedup 1.0000x reference)
//
#include <hip/hip_runtime.h>
#include <hip/hip_bf16.h>
#include <stdint.h>

// PairRelationEncoder: out[b,e,s] = b2[s] + sum_r W2[s,r]*relu(b1[r] + sum_f W1[r,f]*pair[b,e,f])
// pair = [zi, zj, zi-zj, zi*zj] folded to [zi, zj, zi*zj]: Wzi=W1a+W1c, Wzj=W1b-W1c, Wpr=W1d.
// B=4 N=4096 D=64 E=131072 R=64. Out f32 (4,131072,64).
//
// R12: 4 BLOCKS/CU. R10's LDS (41472B) was 512B over the 40960B = 160K/4 threshold; the
// 512B was bias tables. Now: LDS carved manually = 32768 (weights) + 8192 (h1) = 40960
// exactly -> 4 blocks/CU = 16 waves/CU (was 3/12). Bias init = global broadcast loads from
// the prepacked image (L1-resident, no LDS, no held regs). Weight staging via
// global_load_lds width=16 (linear LDS dest per wave). Body = R10 verbatim, cap (256,4).

typedef __attribute__((ext_vector_type(8))) __bf16 bf16x8;
typedef __attribute__((ext_vector_type(4))) __bf16 bf16x4;
typedef __attribute__((ext_vector_type(4))) float  f32x4;

#define E_TOT 131072
#define N_TOK 4096
#define ROWS_PER_BLOCK 256
#define NSUB 4   // per wave: 4 subtiles x 16 pairs (4 waves -> 256 rows/block)
#define Z_ELEMS (4 * N_TOK * 64)
#define WIMG_OFF (Z_ELEMS * 2)          // byte offset of weight image in d_ws (after bf16 z)
#define WIMG_B1 32768                   // f32[64]
#define WIMG_B2 33024                   // f32[64]

__device__ __forceinline__ bf16x8 pk8(float4 a, float4 b) {
    bf16x8 r;
    r[0] = (__bf16)a.x; r[1] = (__bf16)a.y; r[2] = (__bf16)a.z; r[3] = (__bf16)a.w;
    r[4] = (__bf16)b.x; r[5] = (__bf16)b.y; r[6] = (__bf16)b.z; r[7] = (__bf16)b.w;
    return r;
}
__device__ __forceinline__ float4 f4add(float4 a, float4 b){ return make_float4(a.x+b.x, a.y+b.y, a.z+b.z, a.w+b.w); }
__device__ __forceinline__ float4 f4sub(float4 a, float4 b){ return make_float4(a.x-b.x, a.y-b.y, a.z-b.z, a.w-b.w); }

// ---- prep: blocks 0..511 cast z f32->bf16; block 512 packs the swizzled weight image ----
__global__ __launch_bounds__(256) void prep_kernel(
    const float* __restrict__ z, const float* __restrict__ W1, const float* __restrict__ b1,
    const float* __restrict__ W2, const float* __restrict__ b2,
    __bf16* __restrict__ zw, char* __restrict__ wimg)
{
    const int tid = threadIdx.x;
    const int blk = blockIdx.x;
    if (blk < 512) {
        const int t = blk * 256 + tid;
        const float4 a = ((const float4*)z)[2 * t];
        const float4 b = ((const float4*)z)[2 * t + 1];
        ((bf16x8*)zw)[t] = pk8(a, b);
        return;
    }
    const int part = tid >> 6;            // 0:zi 1:zj 2:pr 3:W2
    const int scol = tid & 63;
    const int cswz = (scol & 7) << 4;
    if (part < 3) {
        const float* wr = W1 + (size_t)scol * 256;
        char* dst = wimg + scol * 384;
#pragma unroll
        for (int c8 = 0; c8 < 8; ++c8) {
            float4 p0, p1;
            if (part == 0) {
                float4 a0 = *(const float4*)(wr + c8*8);
                float4 a1 = *(const float4*)(wr + c8*8 + 4);
                float4 c0 = *(const float4*)(wr + 128 + c8*8);
                float4 c1 = *(const float4*)(wr + 128 + c8*8 + 4);
                p0 = f4add(a0, c0); p1 = f4add(a1, c1);
            } else if (part == 1) {
                float4 a0 = *(const float4*)(wr + 64 + c8*8);
                float4 a1 = *(const float4*)(wr + 64 + c8*8 + 4);
                float4 c0 = *(const float4*)(wr + 128 + c8*8);
                float4 c1 = *(const float4*)(wr + 128 + c8*8 + 4);
                p0 = f4sub(a0, c0); p1 = f4sub(a1, c1);
            } else {
                p0 = *(const float4*)(wr + 192 + c8*8);
                p1 = *(const float4*)(wr + 192 + c8*8 + 4);
            }
            *(bf16x8*)(dst + ((part * 128 + c8 * 16) ^ cswz)) = pk8(p0, p1);
        }
    } else {
        const float* wr = W2 + (size_t)scol * 64;
        char* dst = wimg + 24576 + scol * 128;
#pragma unroll
        for (int c8 = 0; c8 < 8; ++c8) {
            float4 p0 = *(const float4*)(wr + c8*8);
            float4 p1 = *(const float4*)(wr + c8*8 + 4);
            *(bf16x8*)(dst + ((c8 * 16) ^ cswz)) = pk8(p0, p1);
        }
    }
    if (tid < 64)            *(float*)(wimg + WIMG_B1 + 4 * tid) = b1[tid];
    else if (tid < 128)      *(float*)(wimg + WIMG_B2 + 4 * (tid - 64)) = b2[tid - 64];
}

__device__ __forceinline__ f32x4 mfma16(bf16x8 a, bf16x8 b, f32x4 c) {
    return __builtin_amdgcn_mfma_f32_16x16x32_bf16(a, b, c, 0, 0, 0);
}

__device__ __forceinline__ bf16x8 bmul(bf16x8 a, bf16x8 b) {
    bf16x8 r;
#pragma unroll
    for (int t = 0; t < 8; ++t)
        r[t] = (__bf16)((float)a[t] * (float)b[t]);
    return r;
}

__global__ __launch_bounds__(256, 4) void PairRelationEncoder_62775241998442_kernel(
    const __bf16* __restrict__ zw, const char* __restrict__ wimg,
    const int* __restrict__ pairs, float* __restrict__ out)
{
    const int tid  = threadIdx.x;
    const int wave = tid >> 6;
    const int lane = tid & 63;
    const int x = lane & 15;   // e-index within subtile (B-col / C-col)
    const int g = lane >> 4;   // k-group

    // bijective XCD-chunked swizzle (2048 blocks, 8 XCDs)
    const int bid = (int)(blockIdx.x & 7) * 256 + ((int)blockIdx.x >> 3);
    const int m0 = bid * ROWS_PER_BLOCK;
    const int b  = m0 >> 17;
    const int e0 = m0 & (E_TOT - 1);
    const __bf16* zb = zw + ((size_t)b * N_TOK * 64);

    // hoisted pairs
    int2 ijv[NSUB];
#pragma unroll
    for (int st = 0; st < NSUB; ++st)
        ijv[st] = *(const int2*)(pairs + 2 * (size_t)(e0 + (st * 4 + wave) * 16 + x));

    // LDS: manually carved 40960 B = 160K/4 exactly -> 4 blocks/CU.
    // [0,32768): weight image (w1 24576 | w2 8192); [32768,40960): per-wave h1 (2048 B each).
    __shared__ char lds[40960];
    const char* w1b = lds;
    const char* w2b = lds + 24576;
    char* h1w = lds + 32768 + wave * 2048;

    // ---- staging: 8x global_load_lds dwordx4 (LDS dest linear per wave: base+lane*16) ----
#pragma unroll
    for (int r = 0; r < 8; ++r) {
        const int goff = (r * 256 + tid) * 16;
        const int lbase = r * 4096 + wave * 1024;     // wave-uniform
        __builtin_amdgcn_global_load_lds(
            (const __attribute__((address_space(1))) void*)(wimg + goff),
            (__attribute__((address_space(3))) void*)(lds + lbase),
            16, 0, 0);
    }

    __syncthreads();

    const int sw = (x & 7) << 4;
    const float* bias1 = (const float*)(wimg + WIMG_B1);
    const float* bias2 = (const float*)(wimg + WIMG_B2);

#pragma unroll
    for (int st = 0; st < NSUB; ++st) {
        const __bf16* zri = zb + (size_t)ijv[st].x * 64;
        const __bf16* zrj = zb + (size_t)ijv[st].y * 64;

        // ---- layer 1 (transposed): acc[ct][q] = h1[r=ct*16+g*4+q][e=x], init = b1 (L1 bcast) ----
        f32x4 acc[4];
#pragma unroll
        for (int ct = 0; ct < 4; ++ct)
            acc[ct] = *(const f32x4*)(bias1 + ct * 16 + g * 4);

#pragma unroll
        for (int h = 0; h < 2; ++h) {
            // per-h JIT gather: 3 live frags (12 regs)
            bf16x8 azf = *(const bf16x8*)(zri + h * 32 + g * 8);   // zi half
            bf16x8 bzf = *(const bf16x8*)(zrj + h * 32 + g * 8);   // zj half
            bf16x8 pzf = bmul(azf, bzf);                            // zi*zj half
            const int kb = h * 64 + g * 16;
#pragma unroll
            for (int ct = 0; ct < 4; ++ct) {
                const int colr = ct * 16 + x;
                const int cswz = (colr & 7) << 4;
                const char* wb = w1b + colr * 384;
                bf16x8 wzi = *(const bf16x8*)(wb + ((kb      ) ^ cswz));
                bf16x8 wzj = *(const bf16x8*)(wb + ((kb + 128) ^ cswz));
                bf16x8 wpr = *(const bf16x8*)(wb + ((kb + 256) ^ cswz));
                acc[ct] = mfma16(wzi, azf, acc[ct]);
                acc[ct] = mfma16(wzj, bzf, acc[ct]);
                acc[ct] = mfma16(wpr, pzf, acc[ct]);
            }
        }

        // ---- epilogue: relu, pack 4xbf16, one ds_write_b64 per ct (wave-private) ----
#pragma unroll
        for (int ct = 0; ct < 4; ++ct) {
            bf16x4 p;
#pragma unroll
            for (int q = 0; q < 4; ++q)
                p[q] = (__bf16)fmaxf(acc[ct][q], 0.f);
            const int wo = (x * 128 + ct * 32 + g * 8) ^ sw;
            *(bf16x4*)(h1w + wo) = p;
        }

        // ---- layer 2 (transposed): o[ct][q] = out[e=x][s=ct*16+g*4+q], init = b2 (L1 bcast) ----
        f32x4 o[4];
#pragma unroll
        for (int ct = 0; ct < 4; ++ct)
            o[ct] = *(const f32x4*)(bias2 + ct * 16 + g * 4);

#pragma unroll
        for (int kk = 0; kk < 2; ++kk) {
            const int aoff = (x * 128 + kk * 64 + g * 16) ^ sw;
            const bf16x8 h1f = *(const bf16x8*)(h1w + aoff);
#pragma unroll
            for (int ct = 0; ct < 4; ++ct) {
                const int cols = ct * 16 + x;
                const bf16x8 w2f = *(const bf16x8*)(w2b + cols * 128
                                                    + ((kk * 64 + g * 16) ^ ((cols & 7) << 4)));
                o[ct] = mfma16(w2f, h1f, o[ct]);
            }
        }

        // ---- store: 4x global_store_dwordx4 ----
        float* orow = out + ((size_t)(m0 + (st * 4 + wave) * 16 + x)) * 64;
#pragma unroll
        for (int ct = 0; ct < 4; ++ct)
            *(f32x4*)(orow + ct * 16 + g * 4) = o[ct];
    }
}

extern "C" void kernel_launch(void* const* d_in, const int* in_sizes, int n_in,
                              void* d_out, int out_size, void* d_ws, size_t ws_size,
                              hipStream_t stream) {
    const float* z     = (const float*)d_in[0];
    const int*   pairs = (const int*)  d_in[1];
    const float* W1    = (const float*)d_in[2];
    const float* b1    = (const float*)d_in[3];
    const float* W2    = (const float*)d_in[4];
    const float* b2    = (const float*)d_in[5];
    float* out = (float*)d_out;
    __bf16* zw  = (__bf16*)d_ws;                   // 2 MB bf16 copy of z
    char*   img = (char*)d_ws + WIMG_OFF;          // 33.3 KB packed weight image + biases

    prep_kernel<<<513, 256, 0, stream>>>(z, W1, b1, W2, b2, zw, img);

    const int total_rows = 4 * E_TOT;              // 524288
    dim3 grid(total_rows / ROWS_PER_BLOCK);        // 2048
    PairRelationEncoder_62775241998442_kernel<<<grid, 256, 0, stream>>>(
        zw, img, pairs, out);
}

// Round 13
// 50.344 us; speedup vs baseline: 1.0502x; 1.0502x over previous
//
#include <hip/hip_runtime.h>
#include <hip/hip_bf16.h>
#include <stdint.h>

// PairRelationEncoder: out[b,e,s] = b2[s] + sum_r W2[s,r]*relu(b1[r] + sum_f W1[r,f]*pair[b,e,f])
// pair = [zi, zj, zi-zj, zi*zj] folded to [zi, zj, zi*zj]: Wzi=W1a+W1c, Wzj=W1b-W1c, Wpr=W1d.
// B=4 N=4096 D=64 E=131072 R=64. Out f32 (4,131072,64).
//
// R13: R10's proven head (prep kernel, pure-copy staging, 2048 blocks) + R9's 32x32
// register-handoff body (cvt_pk_bf16 + permlane32_swap, no h1 LDS roundtrip). Theory:
// runtime ~= SUM of pipe occupancies (nothing saturates); top items are LDS traffic
// (88 ops/32 pairs in R10 ~= 28us) and h1-roundtrip lgkm drains. This body: 48 LDS ops
// per 32 pairs, zero h1 ops, regs ~105 < cap 128 (256,4), LDS 33.3KB -> 4 blocks/CU.

typedef __attribute__((ext_vector_type(8)))  __bf16 bf16x8;
typedef __attribute__((ext_vector_type(4)))  float  f32x4;
typedef __attribute__((ext_vector_type(16))) float  f32x16;
typedef __attribute__((ext_vector_type(4)))  uint32_t u32x4;

#define E_TOT 131072
#define N_TOK 4096
#define ROWS_PER_BLOCK 256
#define NSUB 2            // per wave: 2 subtiles x 32 pairs (4 waves -> 256 rows/block)
#define Z_ELEMS (4 * N_TOK * 64)
#define WIMG_OFF (Z_ELEMS * 2)          // byte offset of weight image in d_ws
#define WIMG_B1 32768                   // f32[64] linear
#define WIMG_B2 33024                   // f32[64] linear

__device__ __forceinline__ bf16x8 pk8(float4 a, float4 b) {
    bf16x8 r;
    r[0] = (__bf16)a.x; r[1] = (__bf16)a.y; r[2] = (__bf16)a.z; r[3] = (__bf16)a.w;
    r[4] = (__bf16)b.x; r[5] = (__bf16)b.y; r[6] = (__bf16)b.z; r[7] = (__bf16)b.w;
    return r;
}
__device__ __forceinline__ float4 f4add(float4 a, float4 b){ return make_float4(a.x+b.x, a.y+b.y, a.z+b.z, a.w+b.w); }
__device__ __forceinline__ float4 f4sub(float4 a, float4 b){ return make_float4(a.x-b.x, a.y-b.y, a.z-b.z, a.w-b.w); }

// ---- prep: blocks 0..511 cast z f32->bf16; block 512 packs the swizzled weight image ----
__global__ __launch_bounds__(256) void prep_kernel(
    const float* __restrict__ z, const float* __restrict__ W1, const float* __restrict__ b1,
    const float* __restrict__ W2, const float* __restrict__ b2,
    __bf16* __restrict__ zw, char* __restrict__ wimg)
{
    const int tid = threadIdx.x;
    const int blk = blockIdx.x;
    if (blk < 512) {
        const int t = blk * 256 + tid;
        const float4 a = ((const float4*)z)[2 * t];
        const float4 b = ((const float4*)z)[2 * t + 1];
        ((bf16x8*)zw)[t] = pk8(a, b);
        return;
    }
    const int part = tid >> 6;            // 0:zi 1:zj 2:pr 3:W2
    const int scol = tid & 63;
    const int cswz = (scol & 7) << 4;
    if (part < 3) {
        const float* wr = W1 + (size_t)scol * 256;
        char* dst = wimg + scol * 384;
#pragma unroll
        for (int c8 = 0; c8 < 8; ++c8) {
            float4 p0, p1;
            if (part == 0) {
                float4 a0 = *(const float4*)(wr + c8*8);
                float4 a1 = *(const float4*)(wr + c8*8 + 4);
                float4 c0 = *(const float4*)(wr + 128 + c8*8);
                float4 c1 = *(const float4*)(wr + 128 + c8*8 + 4);
                p0 = f4add(a0, c0); p1 = f4add(a1, c1);
            } else if (part == 1) {
                float4 a0 = *(const float4*)(wr + 64 + c8*8);
                float4 a1 = *(const float4*)(wr + 64 + c8*8 + 4);
                float4 c0 = *(const float4*)(wr + 128 + c8*8);
                float4 c1 = *(const float4*)(wr + 128 + c8*8 + 4);
                p0 = f4sub(a0, c0); p1 = f4sub(a1, c1);
            } else {
                p0 = *(const float4*)(wr + 192 + c8*8);
                p1 = *(const float4*)(wr + 192 + c8*8 + 4);
            }
            *(bf16x8*)(dst + ((part * 128 + c8 * 16) ^ cswz)) = pk8(p0, p1);
        }
    } else {
        const float* wr = W2 + (size_t)scol * 64;
        char* dst = wimg + 24576 + scol * 128;
#pragma unroll
        for (int c8 = 0; c8 < 8; ++c8) {
            float4 p0 = *(const float4*)(wr + c8*8);
            float4 p1 = *(const float4*)(wr + c8*8 + 4);
            *(bf16x8*)(dst + ((c8 * 16) ^ cswz)) = pk8(p0, p1);
        }
    }
    if (tid < 64)            *(float*)(wimg + WIMG_B1 + 4 * tid) = b1[tid];
    else if (tid < 128)      *(float*)(wimg + WIMG_B2 + 4 * (tid - 64)) = b2[tid - 64];
}

__device__ __forceinline__ f32x16 mfma32(bf16x8 a, bf16x8 b, f32x16 c) {
    return __builtin_amdgcn_mfma_f32_32x32x16_bf16(a, b, c, 0, 0, 0);
}

__device__ __forceinline__ bf16x8 bmul(bf16x8 a, bf16x8 b) {
    bf16x8 r;
#pragma unroll
    for (int t = 0; t < 8; ++t)
        r[t] = (__bf16)((float)a[t] * (float)b[t]);
    return r;
}

__device__ __forceinline__ uint32_t cvtpk(float lo, float hi) {
    uint32_t w;
    asm("v_cvt_pk_bf16_f32 %0, %1, %2" : "=v"(w) : "v"(lo), "v"(hi));
    return w;
}

// relu + pack one rt's 16 accumulators into two layer-2 B-frags (verified R6/R7/R9).
__device__ __forceinline__ void epi(const f32x16 acc, bf16x8& fA, bf16x8& fB) {
    float v[16];
#pragma unroll
    for (int t = 0; t < 16; ++t) v[t] = fmaxf(acc[t], 0.f);
    uint32_t w00 = cvtpk(v[0],  v[1]);
    uint32_t w01 = cvtpk(v[2],  v[3]);
    uint32_t w10 = cvtpk(v[4],  v[5]);
    uint32_t w11 = cvtpk(v[6],  v[7]);
    uint32_t w20 = cvtpk(v[8],  v[9]);
    uint32_t w21 = cvtpk(v[10], v[11]);
    uint32_t w30 = cvtpk(v[12], v[13]);
    uint32_t w31 = cvtpk(v[14], v[15]);
    asm("v_permlane32_swap_b32 %0, %1" : "+v"(w00), "+v"(w10));
    asm("v_permlane32_swap_b32 %0, %1" : "+v"(w01), "+v"(w11));
    asm("v_permlane32_swap_b32 %0, %1" : "+v"(w20), "+v"(w30));
    asm("v_permlane32_swap_b32 %0, %1" : "+v"(w21), "+v"(w31));
    u32x4 a = {w00, w01, w10, w11};
    u32x4 b = {w20, w21, w30, w31};
    fA = __builtin_bit_cast(bf16x8, a);
    fB = __builtin_bit_cast(bf16x8, b);
}

__device__ __forceinline__ f32x16 bias_init(const float* tb, int base) {
    f32x16 a;
#pragma unroll
    for (int p = 0; p < 4; ++p) {
        f32x4 c = *(const f32x4*)(tb + base + 4 * p);
        a[4*p+0] = c[0]; a[4*p+1] = c[1]; a[4*p+2] = c[2]; a[4*p+3] = c[3];
    }
    return a;
}

__global__ __launch_bounds__(256, 4) void PairRelationEncoder_62775241998442_kernel(
    const __bf16* __restrict__ zw, const char* __restrict__ wimg,
    const int* __restrict__ pairs, float* __restrict__ out)
{
    const int tid  = threadIdx.x;
    const int wave = tid >> 6;
    const int lane = tid & 63;
    const int el = lane & 31;   // MFMA row (A) / col (B,C)
    const int hi = lane >> 5;   // k-half

    // bijective XCD-chunked swizzle (2048 blocks, 8 XCDs)
    const int bid = (int)(blockIdx.x & 7) * 256 + ((int)blockIdx.x >> 3);
    const int m0 = bid * ROWS_PER_BLOCK;
    const int b  = m0 >> 17;
    const int e0 = m0 & (E_TOT - 1);
    const __bf16* zb = zw + ((size_t)b * N_TOK * 64);

    // hoisted pairs
    int2 ijv[NSUB];
#pragma unroll
    for (int st = 0; st < NSUB; ++st)
        ijv[st] = *(const int2*)(pairs + 2 * (size_t)(e0 + (st * 4 + wave) * 32 + el));

    // LDS: weight image 32768 (w1 24576 | w2 8192) + permuted bias tables 512 = 33280 B
    // -> 4 blocks/CU (with VGPR <= 128: 16 waves/CU).
    __shared__ char lds[33280];
    const char* w1b = lds;
    const char* w2b = lds + 24576;
    float* tb1 = (float*)(lds + 32768);
    float* tb2 = (float*)(lds + 33024);

    // ---- staging = pure copy of the prepacked image (proven R10 pattern) ----
#pragma unroll
    for (int r = 0; r < 8; ++r) {
        const int off = (r * 256 + tid) * 16;
        float4 v = *(const float4*)(wimg + off);
        *(float4*)(lds + off) = v;
    }
    // permuted bias tables: tb[hi*32+rt*16+reg] = bias[rt*32+(reg&3)+8*((reg>>2)&3)+4*hi]
    if (tid < 64)
        tb1[tid] = *(const float*)(wimg + WIMG_B1 +
                   4 * (((tid >> 4) & 1) * 32 + (tid & 3) + 8 * ((tid >> 2) & 3) + 4 * (tid >> 5)));
    else if (tid < 128) {
        const int t = tid - 64;
        tb2[t] = *(const float*)(wimg + WIMG_B2 +
                 4 * (((t >> 4) & 1) * 32 + (t & 3) + 8 * ((t >> 2) & 3) + 4 * (t >> 5)));
    }

    __syncthreads();

    const int sw = (el & 7) << 4;

#pragma unroll
    for (int st = 0; st < NSUB; ++st) {
        const __bf16* zri = zb + (size_t)ijv[st].x * 64;
        const __bf16* zrj = zb + (size_t)ijv[st].y * 64;

        // ---- layer 1: h1^T[r][e], 24 MFMA over K=192; quarter-JIT gather (12 live regs) ----
        f32x16 acc0 = bias_init(tb1, hi * 32);        // rt=0: r 0..31
        f32x16 acc1 = bias_init(tb1, hi * 32 + 16);   // rt=1: r 32..63

#pragma unroll
        for (int q = 0; q < 4; ++q) {
            bf16x8 ziq = *(const bf16x8*)(zri + q * 16 + hi * 8);   // kt = q
            bf16x8 zjq = *(const bf16x8*)(zrj + q * 16 + hi * 8);   // kt = 4+q
            bf16x8 pq  = bmul(ziq, zjq);                             // kt = 8+q
            {
                const int ko = (q * 32 + hi * 16) ^ sw;
                acc0 = mfma32(*(const bf16x8*)(w1b + (size_t)el * 384        + ko), ziq, acc0);
                acc1 = mfma32(*(const bf16x8*)(w1b + (size_t)(32 + el) * 384 + ko), ziq, acc1);
            }
            {
                const int ko = ((4 + q) * 32 + hi * 16) ^ sw;
                acc0 = mfma32(*(const bf16x8*)(w1b + (size_t)el * 384        + ko), zjq, acc0);
                acc1 = mfma32(*(const bf16x8*)(w1b + (size_t)(32 + el) * 384 + ko), zjq, acc1);
            }
            {
                const int ko = ((8 + q) * 32 + hi * 16) ^ sw;
                acc0 = mfma32(*(const bf16x8*)(w1b + (size_t)el * 384        + ko), pq, acc0);
                acc1 = mfma32(*(const bf16x8*)(w1b + (size_t)(32 + el) * 384 + ko), pq, acc1);
            }
        }

        // ---- hand-off in registers: relu + cvt_pk + permlane32_swap -> 4 B-frags (K=64) ----
        bf16x8 F0, F1, F2, F3;
        epi(acc0, F0, F1);
        epi(acc1, F2, F3);

        // ---- layer 2: out^T[s][e], 8 MFMA over K=64 ----
        f32x16 o0 = bias_init(tb2, hi * 32);          // s 0..31
        f32x16 o1 = bias_init(tb2, hi * 32 + 16);     // s 32..63

#pragma unroll
        for (int k2 = 0; k2 < 4; ++k2) {
            bf16x8 pf = (k2 == 0) ? F0 : (k2 == 1) ? F1 : (k2 == 2) ? F2 : F3;
            const int ko = (k2 * 32 + hi * 16) ^ sw;
            bf16x8 a0 = *(const bf16x8*)(w2b + (size_t)el * 128        + ko);
            bf16x8 a1 = *(const bf16x8*)(w2b + (size_t)(32 + el) * 128 + ko);
            o0 = mfma32(a0, pf, o0);
            o1 = mfma32(a1, pf, o1);
        }

        // ---- store: 8x global_store_dwordx4 (verified R6/R7/R9 layout) ----
        float* orow = out + ((size_t)(m0 + (st * 4 + wave) * 32 + el)) * 64;
#pragma unroll
        for (int p = 0; p < 4; ++p) {
            f32x4 s0v = {o0[4*p], o0[4*p+1], o0[4*p+2], o0[4*p+3]};
            f32x4 s1v = {o1[4*p], o1[4*p+1], o1[4*p+2], o1[4*p+3]};
            *(f32x4*)(orow +      8 * p + 4 * hi) = s0v;
            *(f32x4*)(orow + 32 + 8 * p + 4 * hi) = s1v;
        }
    }
}

extern "C" void kernel_launch(void* const* d_in, const int* in_sizes, int n_in,
                              void* d_out, int out_size, void* d_ws, size_t ws_size,
                              hipStream_t stream) {
    const float* z     = (const float*)d_in[0];
    const int*   pairs = (const int*)  d_in[1];
    const float* W1    = (const float*)d_in[2];
    const float* b1    = (const float*)d_in[3];
    const float* W2    = (const float*)d_in[4];
    const float* b2    = (const float*)d_in[5];
    float* out = (float*)d_out;
    __bf16* zw  = (__bf16*)d_ws;                   // 2 MB bf16 copy of z
    char*   img = (char*)d_ws + WIMG_OFF;          // packed weight image + biases

    prep_kernel<<<513, 256, 0, stream>>>(z, W1, b1, W2, b2, zw, img);

    const int total_rows = 4 * E_TOT;              // 524288
    dim3 grid(total_rows / ROWS_PER_BLOCK);        // 2048
    PairRelationEncoder_62775241998442_kernel<<<grid, 256, 0, stream>>>(
        zw, img, pairs, out);
}

// Round 14
// 45.275 us; speedup vs baseline: 1.1677x; 1.1119x over previous
//
#include <hip/hip_runtime.h>
#include <hip/hip_bf16.h>
#include <stdint.h>

// PairRelationEncoder: out[b,e,s] = b2[s] + sum_r W2[s,r]*relu(b1[r] + sum_f W1[r,f]*pair[b,e,f])
// pair = [zi, zj, zi-zj, zi*zj] folded to [zi, zj, zi*zj]: Wzi=W1a+W1c, Wzj=W1b-W1c, Wpr=W1d.
// B=4 N=4096 D=64 E=131072 R=64. Out f32 (4,131072,64).
//
// R14: OCCUPANCY ISOLATED. R10 body+head verbatim; only change: 512-thread blocks
// (8 waves, NSUB=4, 512 rows/block, grid 1024). LDS 49664B -> 2 blocks/CU; VGPR<=128
// (cap (512,4) = same 128-reg budget as R10) -> 16 waves/CU vs R10's LDS-capped 12.
// Also halves per-CU staging traffic and makes block rounds exactly 2.0.

typedef __attribute__((ext_vector_type(8))) __bf16 bf16x8;
typedef __attribute__((ext_vector_type(4))) __bf16 bf16x4;
typedef __attribute__((ext_vector_type(4))) float  f32x4;

#define E_TOT 131072
#define N_TOK 4096
#define ROWS_PER_BLOCK 512
#define NSUB 4   // per wave: 4 subtiles x 16 pairs (8 waves -> 512 rows/block)
#define Z_ELEMS (4 * N_TOK * 64)
#define WIMG_OFF (Z_ELEMS * 2)          // byte offset of weight image in d_ws (after bf16 z)
#define WIMG_B1 32768                   // f32[64]
#define WIMG_B2 33024                   // f32[64]

__device__ __forceinline__ bf16x8 pk8(float4 a, float4 b) {
    bf16x8 r;
    r[0] = (__bf16)a.x; r[1] = (__bf16)a.y; r[2] = (__bf16)a.z; r[3] = (__bf16)a.w;
    r[4] = (__bf16)b.x; r[5] = (__bf16)b.y; r[6] = (__bf16)b.z; r[7] = (__bf16)b.w;
    return r;
}
__device__ __forceinline__ float4 f4add(float4 a, float4 b){ return make_float4(a.x+b.x, a.y+b.y, a.z+b.z, a.w+b.w); }
__device__ __forceinline__ float4 f4sub(float4 a, float4 b){ return make_float4(a.x-b.x, a.y-b.y, a.z-b.z, a.w-b.w); }

// ---- prep: blocks 0..511 cast z f32->bf16; block 512 packs the swizzled weight image ----
__global__ __launch_bounds__(256) void prep_kernel(
    const float* __restrict__ z, const float* __restrict__ W1, const float* __restrict__ b1,
    const float* __restrict__ W2, const float* __restrict__ b2,
    __bf16* __restrict__ zw, char* __restrict__ wimg)
{
    const int tid = threadIdx.x;
    const int blk = blockIdx.x;
    if (blk < 512) {
        const int t = blk * 256 + tid;
        const float4 a = ((const float4*)z)[2 * t];
        const float4 b = ((const float4*)z)[2 * t + 1];
        ((bf16x8*)zw)[t] = pk8(a, b);
        return;
    }
    const int part = tid >> 6;            // 0:zi 1:zj 2:pr 3:W2
    const int scol = tid & 63;
    const int cswz = (scol & 7) << 4;
    if (part < 3) {
        const float* wr = W1 + (size_t)scol * 256;
        char* dst = wimg + scol * 384;
#pragma unroll
        for (int c8 = 0; c8 < 8; ++c8) {
            float4 p0, p1;
            if (part == 0) {
                float4 a0 = *(const float4*)(wr + c8*8);
                float4 a1 = *(const float4*)(wr + c8*8 + 4);
                float4 c0 = *(const float4*)(wr + 128 + c8*8);
                float4 c1 = *(const float4*)(wr + 128 + c8*8 + 4);
                p0 = f4add(a0, c0); p1 = f4add(a1, c1);
            } else if (part == 1) {
                float4 a0 = *(const float4*)(wr + 64 + c8*8);
                float4 a1 = *(const float4*)(wr + 64 + c8*8 + 4);
                float4 c0 = *(const float4*)(wr + 128 + c8*8);
                float4 c1 = *(const float4*)(wr + 128 + c8*8 + 4);
                p0 = f4sub(a0, c0); p1 = f4sub(a1, c1);
            } else {
                p0 = *(const float4*)(wr + 192 + c8*8);
                p1 = *(const float4*)(wr + 192 + c8*8 + 4);
            }
            *(bf16x8*)(dst + ((part * 128 + c8 * 16) ^ cswz)) = pk8(p0, p1);
        }
    } else {
        const float* wr = W2 + (size_t)scol * 64;
        char* dst = wimg + 24576 + scol * 128;
#pragma unroll
        for (int c8 = 0; c8 < 8; ++c8) {
            float4 p0 = *(const float4*)(wr + c8*8);
            float4 p1 = *(const float4*)(wr + c8*8 + 4);
            *(bf16x8*)(dst + ((c8 * 16) ^ cswz)) = pk8(p0, p1);
        }
    }
    if (tid < 64)            *(float*)(wimg + WIMG_B1 + 4 * tid) = b1[tid];
    else if (tid < 128)      *(float*)(wimg + WIMG_B2 + 4 * (tid - 64)) = b2[tid - 64];
}

__device__ __forceinline__ f32x4 mfma16(bf16x8 a, bf16x8 b, f32x4 c) {
    return __builtin_amdgcn_mfma_f32_16x16x32_bf16(a, b, c, 0, 0, 0);
}

__device__ __forceinline__ bf16x8 bmul(bf16x8 a, bf16x8 b) {
    bf16x8 r;
#pragma unroll
    for (int t = 0; t < 8; ++t)
        r[t] = (__bf16)((float)a[t] * (float)b[t]);
    return r;
}

__global__ __launch_bounds__(512, 4) void PairRelationEncoder_62775241998442_kernel(
    const __bf16* __restrict__ zw, const char* __restrict__ wimg,
    const int* __restrict__ pairs, float* __restrict__ out)
{
    const int tid  = threadIdx.x;
    const int wave = tid >> 6;
    const int lane = tid & 63;
    const int x = lane & 15;   // e-index within subtile (B-col / C-col)
    const int g = lane >> 4;   // k-group

    // bijective XCD-chunked swizzle (1024 blocks, 8 XCDs)
    const int bid = (int)(blockIdx.x & 7) * 128 + ((int)blockIdx.x >> 3);
    const int m0 = bid * ROWS_PER_BLOCK;
    const int b  = m0 >> 17;
    const int e0 = m0 & (E_TOT - 1);
    const __bf16* zb = zw + ((size_t)b * N_TOK * 64);

    // hoisted pairs
    int2 ijv[NSUB];
#pragma unroll
    for (int st = 0; st < NSUB; ++st)
        ijv[st] = *(const int2*)(pairs + 2 * (size_t)(e0 + (st * 8 + wave) * 16 + x));

    // LDS: weight image (32768) + per-wave h1 (8x2048) + biases (512) = 49664 B
    // -> 2 blocks/CU (LDS); 16 waves/CU at VGPR<=128.
    __shared__ char   wall[32768];
    __shared__ __bf16 h1s[8][1024];
    __shared__ float  b1s[64];
    __shared__ float  b2s[64];
    __bf16* h1w = h1s[wave];
    const char* w1b = wall;
    const char* w2b = wall + 24576;

    // ---- staging = pure copy of the prepacked image: 4x (float4 load + b128 LDS write) ----
#pragma unroll
    for (int r = 0; r < 4; ++r) {
        const int off = (r * 512 + tid) * 16;
        float4 v = *(const float4*)(wimg + off);
        *(float4*)(wall + off) = v;
    }
    if (tid < 64)            b1s[tid] = *(const float*)(wimg + WIMG_B1 + 4 * tid);
    else if (tid < 128)      b2s[tid - 64] = *(const float*)(wimg + WIMG_B2 + 4 * (tid - 64));

    __syncthreads();

    const int sw = (x & 7) << 4;

#pragma unroll
    for (int st = 0; st < NSUB; ++st) {
        const __bf16* zri = zb + (size_t)ijv[st].x * 64;
        const __bf16* zrj = zb + (size_t)ijv[st].y * 64;

        // ---- layer 1 (transposed): acc[ct][q] = h1[r=ct*16+g*4+q][e=x], init = b1 ----
        f32x4 acc[4];
#pragma unroll
        for (int ct = 0; ct < 4; ++ct)
            acc[ct] = *(const f32x4*)(b1s + ct * 16 + g * 4);

#pragma unroll
        for (int h = 0; h < 2; ++h) {
            // per-h JIT gather: 3 live frags (12 regs)
            bf16x8 azf = *(const bf16x8*)(zri + h * 32 + g * 8);   // zi half
            bf16x8 bzf = *(const bf16x8*)(zrj + h * 32 + g * 8);   // zj half
            bf16x8 pzf = bmul(azf, bzf);                            // zi*zj half
            const int kb = h * 64 + g * 16;
#pragma unroll
            for (int ct = 0; ct < 4; ++ct) {
                const int colr = ct * 16 + x;
                const int cswz = (colr & 7) << 4;
                const char* wb = w1b + colr * 384;
                bf16x8 wzi = *(const bf16x8*)(wb + ((kb      ) ^ cswz));
                bf16x8 wzj = *(const bf16x8*)(wb + ((kb + 128) ^ cswz));
                bf16x8 wpr = *(const bf16x8*)(wb + ((kb + 256) ^ cswz));
                acc[ct] = mfma16(wzi, azf, acc[ct]);
                acc[ct] = mfma16(wzj, bzf, acc[ct]);
                acc[ct] = mfma16(wpr, pzf, acc[ct]);
            }
        }

        // ---- epilogue: relu, pack 4xbf16, one ds_write_b64 per ct (wave-private) ----
#pragma unroll
        for (int ct = 0; ct < 4; ++ct) {
            bf16x4 p;
#pragma unroll
            for (int q = 0; q < 4; ++q)
                p[q] = (__bf16)fmaxf(acc[ct][q], 0.f);
            const int wo = (x * 128 + ct * 32 + g * 8) ^ sw;
            *(bf16x4*)((char*)h1w + wo) = p;
        }

        // ---- layer 2 (transposed): o[ct][q] = out[e=x][s=ct*16+g*4+q], init = b2 ----
        f32x4 o[4];
#pragma unroll
        for (int ct = 0; ct < 4; ++ct)
            o[ct] = *(const f32x4*)(b2s + ct * 16 + g * 4);

#pragma unroll
        for (int kk = 0; kk < 2; ++kk) {
            const int aoff = (x * 128 + kk * 64 + g * 16) ^ sw;
            const bf16x8 h1f = *(const bf16x8*)((const char*)h1w + aoff);
#pragma unroll
            for (int ct = 0; ct < 4; ++ct) {
                const int cols = ct * 16 + x;
                const bf16x8 w2f = *(const bf16x8*)(w2b + cols * 128
                                                    + ((kk * 64 + g * 16) ^ ((cols & 7) << 4)));
                o[ct] = mfma16(w2f, h1f, o[ct]);
            }
        }

        // ---- store: 4x global_store_dwordx4 ----
        float* orow = out + ((size_t)(m0 + (st * 8 + wave) * 16 + x)) * 64;
#pragma unroll
        for (int ct = 0; ct < 4; ++ct)
            *(f32x4*)(orow + ct * 16 + g * 4) = o[ct];
    }
}

extern "C" void kernel_launch(void* const* d_in, const int* in_sizes, int n_in,
                              void* d_out, int out_size, void* d_ws, size_t ws_size,
                              hipStream_t stream) {
    const float* z     = (const float*)d_in[0];
    const int*   pairs = (const int*)  d_in[1];
    const float* W1    = (const float*)d_in[2];
    const float* b1    = (const float*)d_in[3];
    const float* W2    = (const float*)d_in[4];
    const float* b2    = (const float*)d_in[5];
    float* out = (float*)d_out;
    __bf16* zw  = (__bf16*)d_ws;                   // 2 MB bf16 copy of z
    char*   img = (char*)d_ws + WIMG_OFF;          // 33.3 KB packed weight image + biases

    prep_kernel<<<513, 256, 0, stream>>>(z, W1, b1, W2, b2, zw, img);

    const int total_rows = 4 * E_TOT;              // 524288
    dim3 grid(total_rows / ROWS_PER_BLOCK);        // 1024
    PairRelationEncoder_62775241998442_kernel<<<grid, 512, 0, stream>>>(
        zw, img, pairs, out);
}